// Round 1
// baseline (892.389 us; speedup 1.0000x reference)
//
#include <hip/hip_runtime.h>

#define E_TOTAL 50000
#define NTILES  3125      // E_TOTAL / 16, exact

typedef float f4  __attribute__((ext_vector_type(4)));
typedef short s8v __attribute__((ext_vector_type(8)));   // 8 bf16 bit-patterns (4 VGPRs)
typedef short s4v __attribute__((ext_vector_type(4)));   // 4 bf16 bit-patterns (2 VGPRs)

__device__ __forceinline__ short f2bf(float x){
  unsigned u = __builtin_bit_cast(unsigned, x);
  u += 0x7fffu + ((u >> 16) & 1u);           // RNE
  return (short)(u >> 16);
}
__device__ __forceinline__ float bf2f(short s){
  unsigned u = ((unsigned)(unsigned short)s) << 16;
  return __builtin_bit_cast(float, u);
}
__device__ __forceinline__ float sigm(float x){ return 1.f/(1.f + __expf(-x)); }

// Load 8 consecutive f32 and convert to a bf16x8 B-fragment (natural k-order).
__device__ __forceinline__ s8v load_bfrag(const float* p){
  f4 a = *(const f4*)p;
  f4 b = *(const f4*)(p + 4);
  s8v r;
  r[0]=f2bf(a[0]); r[1]=f2bf(a[1]); r[2]=f2bf(a[2]); r[3]=f2bf(a[3]);
  r[4]=f2bf(b[0]); r[5]=f2bf(b[1]); r[6]=f2bf(b[2]); r[7]=f2bf(b[3]);
  return r;
}

// D[128 features x 16 edges] += Wt(A, packed) @ B ; 8 m-blocks x 4 k-chunks of MFMA.
__device__ __forceinline__ void mm8(f4* acc, const s8v* B, const short* pa, int lane){
  const s8v* A = (const s8v*)pa;
  #pragma unroll
  for (int mb = 0; mb < 8; ++mb){
    #pragma unroll
    for (int kk = 0; kk < 4; ++kk){
      s8v af = A[(mb*4 + kk)*64 + lane];
      acc[mb] = __builtin_amdgcn_mfma_f32_16x16x32_bf16(af, B[kk], acc[mb], 0, 0, 0);
    }
  }
}

// ---------------------------------------------------------------------------
// Precompute: 14 fragment-ready bf16 A-matrices (A[m][k] = W[k][m], optionally
// W = X@Y fused product), packed so lane reads 16B contiguous per (mblk,kk).
//   mi 0 WqT(nat) | 1 GKT=Wk@Wk1a | 2 GMT=Wv@Wm1a | 3 GKaT=We@Wk1c | 4 GMaT=We@Wm1c
//   mi 5 Wk2T(dlay) | 6 Wm2T(dlay) | 7 WcT(dlay) | 8..10 GKeT[t] | 11..13 GMeT[t]
// dlay order matches the MFMA C/D register layout of the previous stage.
// ---------------------------------------------------------------------------
__global__ __launch_bounds__(256) void pack_weights(
    const float* __restrict__ Wq, const float* __restrict__ Wk, const float* __restrict__ Wv,
    const float* __restrict__ Wke, const float* __restrict__ Wve, const float* __restrict__ We,
    const float* __restrict__ Wc, const float* __restrict__ Wk1, const float* __restrict__ Wk2,
    const float* __restrict__ Wm1, const float* __restrict__ Wm2,
    short* __restrict__ wsm)
{
  int mi   = blockIdx.x >> 6;
  int elem = ((blockIdx.x & 63) << 8) + threadIdx.x;   // 0..16383
  int p  = elem & 7;
  int l  = (elem >> 3) & 63;
  int kk = (elem >> 9) & 3;
  int mb = elem >> 11;
  int gg = l >> 4;
  int m  = mb*16 + (l & 15);
  bool dlay = (mi == 5) || (mi == 6) || (mi == 7);
  int k = dlay ? (kk*32 + ((p < 4) ? (gg*4 + p) : (16 + gg*4 + (p - 4))))
               : (kk*32 + gg*8 + p);

  const float* X = nullptr; const float* Y = nullptr; const float* W = nullptr;
  switch (mi){
    case 0: W = Wq; break;
    case 1: X = Wk; Y = Wk1;            break;
    case 2: X = Wv; Y = Wm1;            break;
    case 3: X = We; Y = Wk1 + 256*128;  break;
    case 4: X = We; Y = Wm1 + 256*128;  break;
    case 5: W = Wk2; break;
    case 6: W = Wm2; break;
    case 7: W = Wc;  break;
    default:
      if (mi < 11){ X = Wke + (mi-8)*16384;  Y = Wk1 + 128*128; }
      else        { X = Wve + (mi-11)*16384; Y = Wm1 + 128*128; }
  }
  float v;
  if (W){
    v = W[k*128 + m];
  } else {
    v = 0.f;
    for (int j = 0; j < 128; ++j) v += X[k*128 + j] * Y[j*128 + m];
  }
  wsm[(size_t)mi*16384 + elem] = f2bf(v);
}

// biasK[t] = bk@Wk1a + bke[t]@Wk1b + bk1 ; biasM[t] = bv@Wm1a + bve[t]@Wm1b + bm1
__global__ __launch_bounds__(128) void make_biases(
    const float* __restrict__ bk,  const float* __restrict__ bke, const float* __restrict__ bk1,
    const float* __restrict__ bv,  const float* __restrict__ bve, const float* __restrict__ bm1,
    const float* __restrict__ Wk1, const float* __restrict__ Wm1,
    float* __restrict__ wsb)
{
  int b = blockIdx.x;          // 0..2 -> biasK[t], 3..5 -> biasM[t]
  int t = b % 3;
  bool isM = b >= 3;
  int o = threadIdx.x;
  const float* W  = isM ? Wm1 : Wk1;
  const float* b0 = isM ? bv  : bk;
  const float* be = (isM ? bve : bke) + t*128;
  const float* b1 = isM ? bm1 : bk1;
  float v = b1[o];
  for (int j = 0; j < 128; ++j)
    v += b0[j]*W[j*128 + o] + be[j]*W[(128 + j)*128 + o];
  wsb[b*128 + o] = v;
}

// ---------------------------------------------------------------------------
// Main fused kernel: 1 wave = 16 edges. Everything in registers, no LDS.
// Orientation: D[m=feature][n=edge]; lane holds edge (lane&15), features
// mb*16 + (lane>>4)*4 + r. LN over C via 2x shfl_xor(16/32).
// ---------------------------------------------------------------------------
__global__ __launch_bounds__(256) void edge_main(
    const float* __restrict__ edge, const float* __restrict__ nlen, const float* __restrict__ nang,
    const float* __restrict__ bq,   const float* __restrict__ bk2,  const float* __restrict__ bm2,
    const float* __restrict__ bc,
    const float* __restrict__ g_att, const float* __restrict__ b_att,
    const float* __restrict__ g_bn,  const float* __restrict__ b_bn,
    const short* __restrict__ wsm,  const float* __restrict__ wsb,
    float* __restrict__ out)
{
  const int lane = threadIdx.x & 63;
  const int wid  = threadIdx.x >> 6;
  const int tile = blockIdx.x*4 + wid;
  if (tile >= NTILES) return;
  const int g  = lane >> 4;
  const int er = lane & 15;
  const size_t e = (size_t)tile*16 + er;
  const float* erow = edge + e*128;

  // ---- edge B-fragments ----
  s8v BE[4];
  #pragma unroll
  for (int kk = 0; kk < 4; ++kk) BE[kk] = load_bfrag(erow + kk*32 + g*8);

  f4 acc[8];
  s4v qb[8], ekb[8], emb[8];

  // q = Wq^T @ edge^T + bq
  #pragma unroll
  for (int mb = 0; mb < 8; ++mb) acc[mb] = *(const f4*)(bq + mb*16 + g*4);
  mm8(acc, BE, wsm + 0*16384, lane);
  #pragma unroll
  for (int mb = 0; mb < 8; ++mb){
    s4v t4; t4[0]=f2bf(acc[mb][0]); t4[1]=f2bf(acc[mb][1]); t4[2]=f2bf(acc[mb][2]); t4[3]=f2bf(acc[mb][3]);
    qb[mb] = t4;
  }
  // ek = GK^T @ edge^T   (bias folded into biasK[t])
  #pragma unroll
  for (int mb = 0; mb < 8; ++mb){ f4 z = {0.f,0.f,0.f,0.f}; acc[mb] = z; }
  mm8(acc, BE, wsm + 1*16384, lane);
  #pragma unroll
  for (int mb = 0; mb < 8; ++mb){
    s4v t4; t4[0]=f2bf(acc[mb][0]); t4[1]=f2bf(acc[mb][1]); t4[2]=f2bf(acc[mb][2]); t4[3]=f2bf(acc[mb][3]);
    ekb[mb] = t4;
  }
  // em = GM^T @ edge^T
  #pragma unroll
  for (int mb = 0; mb < 8; ++mb){ f4 z = {0.f,0.f,0.f,0.f}; acc[mb] = z; }
  mm8(acc, BE, wsm + 2*16384, lane);
  #pragma unroll
  for (int mb = 0; mb < 8; ++mb){
    s4v t4; t4[0]=f2bf(acc[mb][0]); t4[1]=f2bf(acc[mb][1]); t4[2]=f2bf(acc[mb][2]); t4[3]=f2bf(acc[mb][3]);
    emb[mb] = t4;
  }

  f4 gm[8];
  #pragma unroll
  for (int mb = 0; mb < 8; ++mb){ f4 z = {0.f,0.f,0.f,0.f}; gm[mb] = z; }

  for (int t = 0; t < 3; ++t){
    const float* lrow = nlen + (e*3 + t)*128;
    const float* arow = nang + (e*3 + t)*128;
    s8v BL[4], BA[4];
    #pragma unroll
    for (int kk = 0; kk < 4; ++kk){
      BL[kk] = load_bfrag(lrow + kk*32 + g*8);
      BA[kk] = load_bfrag(arow + kk*32 + g*8);
    }

    // ---- key path: h1K = ek + L@GKe[t] + A@GKa + biasK[t] ----
    f4 h[8];
    #pragma unroll
    for (int mb = 0; mb < 8; ++mb){
      f4 b = *(const f4*)(wsb + t*128 + mb*16 + g*4);
      #pragma unroll
      for (int r = 0; r < 4; ++r) b[r] += bf2f(ekb[mb][r]);
      h[mb] = b;
    }
    mm8(h, BL, wsm + (size_t)(8 + t)*16384, lane);
    mm8(h, BA, wsm + 3*16384, lane);

    // silu -> layer-2 B-fragments (dlay order: just pair adjacent m-blocks)
    s8v S[4];
    #pragma unroll
    for (int kk = 0; kk < 4; ++kk){
      #pragma unroll
      for (int p = 0; p < 4; ++p){
        float x0 = h[2*kk][p];   S[kk][p]     = f2bf(x0 * sigm(x0));
        float x1 = h[2*kk+1][p]; S[kk][4 + p] = f2bf(x1 * sigm(x1));
      }
    }
    f4 ka[8];
    #pragma unroll
    for (int mb = 0; mb < 8; ++mb) ka[mb] = *(const f4*)(bk2 + mb*16 + g*4);
    mm8(ka, S, wsm + 5*16384, lane);

    // alpha = q*k/sqrt(C) ; LN over C ; sigmoid gate
    float s = 0.f, ss = 0.f;
    #pragma unroll
    for (int mb = 0; mb < 8; ++mb){
      #pragma unroll
      for (int r = 0; r < 4; ++r){
        float a = bf2f(qb[mb][r]) * ka[mb][r] * 0.08838834764831845f;
        ka[mb][r] = a; s += a; ss += a*a;
      }
    }
    s  += __shfl_xor(s, 16);  s  += __shfl_xor(s, 32);
    ss += __shfl_xor(ss, 16); ss += __shfl_xor(ss, 32);
    float mean = s * (1.f/128.f);
    float var  = ss * (1.f/128.f) - mean*mean;
    float rstd = rsqrtf(var + 1e-5f);
    s4v gateb[8];
    #pragma unroll
    for (int mb = 0; mb < 8; ++mb){
      f4 ga = *(const f4*)(g_att + mb*16 + g*4);
      f4 bb = *(const f4*)(b_att + mb*16 + g*4);
      s4v t4;
      #pragma unroll
      for (int r = 0; r < 4; ++r)
        t4[r] = f2bf(sigm((ka[mb][r] - mean)*rstd*ga[r] + bb[r]));
      gateb[mb] = t4;
    }

    // ---- msg path: h1M = em + L@GMe[t] + A@GMa + biasM[t] ----
    #pragma unroll
    for (int mb = 0; mb < 8; ++mb){
      f4 b = *(const f4*)(wsb + 384 + t*128 + mb*16 + g*4);
      #pragma unroll
      for (int r = 0; r < 4; ++r) b[r] += bf2f(emb[mb][r]);
      h[mb] = b;
    }
    mm8(h, BL, wsm + (size_t)(11 + t)*16384, lane);
    mm8(h, BA, wsm + 4*16384, lane);
    #pragma unroll
    for (int kk = 0; kk < 4; ++kk){
      #pragma unroll
      for (int p = 0; p < 4; ++p){
        float x0 = h[2*kk][p];   S[kk][p]     = f2bf(x0 * sigm(x0));
        float x1 = h[2*kk+1][p]; S[kk][4 + p] = f2bf(x1 * sigm(x1));
      }
    }
    f4 ma[8];
    #pragma unroll
    for (int mb = 0; mb < 8; ++mb) ma[mb] = *(const f4*)(bm2 + mb*16 + g*4);
    mm8(ma, S, wsm + 6*16384, lane);
    #pragma unroll
    for (int mb = 0; mb < 8; ++mb){
      #pragma unroll
      for (int r = 0; r < 4; ++r) gm[mb][r] += ma[mb][r] * bf2f(gateb[mb][r]);
    }
  }

  // ---- out = gm @ Wc + 3*bc ; LN ; softplus(edge + .) ----
  s8v GF[4];
  #pragma unroll
  for (int kk = 0; kk < 4; ++kk){
    #pragma unroll
    for (int p = 0; p < 4; ++p){
      GF[kk][p]     = f2bf(gm[2*kk][p]);
      GF[kk][4 + p] = f2bf(gm[2*kk+1][p]);
    }
  }
  f4 oa[8];
  #pragma unroll
  for (int mb = 0; mb < 8; ++mb){
    f4 b = *(const f4*)(bc + mb*16 + g*4);
    #pragma unroll
    for (int r = 0; r < 4; ++r) b[r] *= 3.f;
    oa[mb] = b;
  }
  mm8(oa, GF, wsm + 7*16384, lane);

  float s = 0.f, ss = 0.f;
  #pragma unroll
  for (int mb = 0; mb < 8; ++mb){
    #pragma unroll
    for (int r = 0; r < 4; ++r){ s += oa[mb][r]; ss += oa[mb][r]*oa[mb][r]; }
  }
  s  += __shfl_xor(s, 16);  s  += __shfl_xor(s, 32);
  ss += __shfl_xor(ss, 16); ss += __shfl_xor(ss, 32);
  float mean = s * (1.f/128.f);
  float var  = ss * (1.f/128.f) - mean*mean;
  float rstd = rsqrtf(var + 1e-5f);

  #pragma unroll
  for (int mb = 0; mb < 8; ++mb){
    f4 ev  = *(const f4*)(erow + mb*16 + g*4);
    f4 gv  = *(const f4*)(g_bn + mb*16 + g*4);
    f4 bv2 = *(const f4*)(b_bn + mb*16 + g*4);
    f4 o;
    #pragma unroll
    for (int r = 0; r < 4; ++r){
      float x = ev[r] + (oa[mb][r] - mean)*rstd*gv[r] + bv2[r];
      o[r] = (x > 20.f) ? x : log1pf(__expf(x));
    }
    *(f4*)(out + e*128 + mb*16 + g*4) = o;
  }
}

extern "C" void kernel_launch(void* const* d_in, const int* in_sizes, int n_in,
                              void* d_out, int out_size, void* d_ws, size_t ws_size,
                              hipStream_t stream)
{
  const float* edge = (const float*)d_in[0];
  const float* nlen = (const float*)d_in[1];
  const float* nang = (const float*)d_in[2];
  const float* Wq  = (const float*)d_in[3];
  const float* bq  = (const float*)d_in[4];
  const float* Wk  = (const float*)d_in[5];
  const float* bk  = (const float*)d_in[6];
  const float* Wv  = (const float*)d_in[7];
  const float* bv  = (const float*)d_in[8];
  const float* Wke = (const float*)d_in[9];
  const float* bke = (const float*)d_in[10];
  const float* Wve = (const float*)d_in[11];
  const float* bve = (const float*)d_in[12];
  const float* We  = (const float*)d_in[13];
  const float* Wc  = (const float*)d_in[14];
  const float* bc  = (const float*)d_in[15];
  const float* Wk1 = (const float*)d_in[16];
  const float* bk1 = (const float*)d_in[17];
  const float* Wk2 = (const float*)d_in[18];
  const float* bk2 = (const float*)d_in[19];
  const float* Wm1 = (const float*)d_in[20];
  const float* bm1 = (const float*)d_in[21];
  const float* Wm2 = (const float*)d_in[22];
  const float* bm2 = (const float*)d_in[23];
  const float* g_att = (const float*)d_in[24];
  const float* b_att = (const float*)d_in[25];
  const float* g_bn  = (const float*)d_in[26];
  const float* b_bn  = (const float*)d_in[27];

  // ws layout: 14 packed bf16 matrices (16384 shorts each) + 6*128 f32 biases
  short* wsm = (short*)d_ws;
  float* wsb = (float*)((char*)d_ws + (size_t)14*16384*2);

  pack_weights<<<dim3(14*64), dim3(256), 0, stream>>>(
      Wq, Wk, Wv, Wke, Wve, We, Wc, Wk1, Wk2, Wm1, Wm2, wsm);
  make_biases<<<dim3(6), dim3(128), 0, stream>>>(
      bk, bke, bk1, bv, bve, bm1, Wk1, Wm1, wsb);
  edge_main<<<dim3((NTILES + 3)/4), dim3(256), 0, stream>>>(
      edge, nlen, nang, bq, bk2, bm2, bc, g_att, b_att, g_bn, b_bn,
      wsm, wsb, (float*)d_out);
}

// Round 2
// 258.058 us; speedup vs baseline: 3.4581x; 3.4581x over previous
//
#include <hip/hip_runtime.h>

#define E_TOTAL 50000
#define NTILES  3125      // E_TOTAL / 16, exact

typedef float f4  __attribute__((ext_vector_type(4)));
typedef short s8v __attribute__((ext_vector_type(8)));   // 8 bf16 bit-patterns (4 VGPRs)
typedef short s4v __attribute__((ext_vector_type(4)));   // 4 bf16 bit-patterns (2 VGPRs)

typedef __attribute__((address_space(3))) unsigned lds_u32;
typedef __attribute__((address_space(1))) const unsigned g_u32;

__device__ __forceinline__ short f2bf(float x){
  unsigned u = __builtin_bit_cast(unsigned, x);
  u += 0x7fffu + ((u >> 16) & 1u);           // RNE
  return (short)(u >> 16);
}
__device__ __forceinline__ float bf2f(short s){
  unsigned u = ((unsigned)(unsigned short)s) << 16;
  return __builtin_bit_cast(float, u);
}
__device__ __forceinline__ float sigm(float x){ return 1.f/(1.f + __expf(-x)); }

// Load 8 consecutive f32 and convert to a bf16x8 B-fragment (natural k-order).
__device__ __forceinline__ s8v load_bfrag(const float* p){
  f4 a = *(const f4*)p;
  f4 b = *(const f4*)(p + 4);
  s8v r;
  r[0]=f2bf(a[0]); r[1]=f2bf(a[1]); r[2]=f2bf(a[2]); r[3]=f2bf(a[3]);
  r[4]=f2bf(b[0]); r[5]=f2bf(b[1]); r[6]=f2bf(b[2]); r[7]=f2bf(b[3]);
  return r;
}

// D[128 features x 16 edges] += A(from LDS) @ B ; 8 m-blocks x 4 k-chunks.
__device__ __forceinline__ void mm8l(f4* acc, const s8v* B, const s8v* A, int lane){
  #pragma unroll
  for (int mb = 0; mb < 8; ++mb){
    #pragma unroll
    for (int kk = 0; kk < 4; ++kk){
      s8v af = A[(mb*4 + kk)*64 + lane];
      acc[mb] = __builtin_amdgcn_mfma_f32_16x16x32_bf16(af, B[kk], acc[mb], 0, 0, 0);
    }
  }
}

// Cooperative 32KB matrix stage: 256 threads x 8 iters x 16B, global->LDS direct.
// LDS dest is wave-uniform base + lane*16; pack layout is linear so this matches.
__device__ __forceinline__ void stage_mat(const short* __restrict__ src,
                                          short* dst, int wid, int lane){
  #pragma unroll
  for (int j = 0; j < 8; ++j){
    const short* gsrc = src + j*2048 + wid*512 + lane*8;   // bytes: j*4096 + wid*1024 + lane*16
    short* ldst = dst + j*2048 + wid*512;                  // wave-uniform
    __builtin_amdgcn_global_load_lds((g_u32*)(const void*)gsrc, (lds_u32*)(void*)ldst, 16, 0, 0);
  }
}

// ---------------------------------------------------------------------------
// Precompute: 14 fragment-ready bf16 A-matrices (A[m][k] = W[k][m], optionally
// W = X@Y fused product), packed so lane reads 16B contiguous per (mblk,kk).
//   mi 0 WqT(nat) | 1 GKT=Wk@Wk1a | 2 GMT=Wv@Wm1a | 3 GKaT=We@Wk1c | 4 GMaT=We@Wm1c
//   mi 5 Wk2T(dlay) | 6 Wm2T(dlay) | 7 WcT(dlay) | 8..10 GKeT[t] | 11..13 GMeT[t]
// ---------------------------------------------------------------------------
__global__ __launch_bounds__(256) void pack_weights(
    const float* __restrict__ Wq, const float* __restrict__ Wk, const float* __restrict__ Wv,
    const float* __restrict__ Wke, const float* __restrict__ Wve, const float* __restrict__ We,
    const float* __restrict__ Wc, const float* __restrict__ Wk1, const float* __restrict__ Wk2,
    const float* __restrict__ Wm1, const float* __restrict__ Wm2,
    short* __restrict__ wsm)
{
  int mi   = blockIdx.x >> 6;
  int elem = ((blockIdx.x & 63) << 8) + threadIdx.x;   // 0..16383
  int p  = elem & 7;
  int l  = (elem >> 3) & 63;
  int kk = (elem >> 9) & 3;
  int mb = elem >> 11;
  int gg = l >> 4;
  int m  = mb*16 + (l & 15);
  bool dlay = (mi == 5) || (mi == 6) || (mi == 7);
  int k = dlay ? (kk*32 + ((p < 4) ? (gg*4 + p) : (16 + gg*4 + (p - 4))))
               : (kk*32 + gg*8 + p);

  const float* X = nullptr; const float* Y = nullptr; const float* W = nullptr;
  switch (mi){
    case 0: W = Wq; break;
    case 1: X = Wk; Y = Wk1;            break;
    case 2: X = Wv; Y = Wm1;            break;
    case 3: X = We; Y = Wk1 + 256*128;  break;
    case 4: X = We; Y = Wm1 + 256*128;  break;
    case 5: W = Wk2; break;
    case 6: W = Wm2; break;
    case 7: W = Wc;  break;
    default:
      if (mi < 11){ X = Wke + (mi-8)*16384;  Y = Wk1 + 128*128; }
      else        { X = Wve + (mi-11)*16384; Y = Wm1 + 128*128; }
  }
  float v;
  if (W){
    v = W[k*128 + m];
  } else {
    v = 0.f;
    for (int j = 0; j < 128; ++j) v += X[k*128 + j] * Y[j*128 + m];
  }
  wsm[(size_t)mi*16384 + elem] = f2bf(v);
}

// biasK[t] = bk@Wk1a + bke[t]@Wk1b + bk1 ; biasM[t] = bv@Wm1a + bve[t]@Wm1b + bm1
__global__ __launch_bounds__(128) void make_biases(
    const float* __restrict__ bk,  const float* __restrict__ bke, const float* __restrict__ bk1,
    const float* __restrict__ bv,  const float* __restrict__ bve, const float* __restrict__ bm1,
    const float* __restrict__ Wk1, const float* __restrict__ Wm1,
    float* __restrict__ wsb)
{
  int b = blockIdx.x;          // 0..2 -> biasK[t], 3..5 -> biasM[t]
  int t = b % 3;
  bool isM = b >= 3;
  int o = threadIdx.x;
  const float* W  = isM ? Wm1 : Wk1;
  const float* b0 = isM ? bv  : bk;
  const float* be = (isM ? bve : bke) + t*128;
  const float* b1 = isM ? bm1 : bk1;
  float v = b1[o];
  for (int j = 0; j < 128; ++j)
    v += b0[j]*W[j*128 + o] + be[j]*W[(128 + j)*128 + o];
  wsb[b*128 + o] = v;
}

// ---------------------------------------------------------------------------
// Main fused kernel: 4 waves/block, 16 edges/wave. 22-phase weight stream
// through double-buffered LDS (2 x 32KB). One acc[8] reused for every stage.
// Orientation: D[m=feature][n=edge]; lane holds edge (lane&15), features
// mb*16 + (lane>>4)*4 + r. LN over C via 2x shfl_xor(16/32).
// ---------------------------------------------------------------------------
__global__ __launch_bounds__(256) void edge_main(
    const float* __restrict__ edge, const float* __restrict__ nlen, const float* __restrict__ nang,
    const float* __restrict__ bq,   const float* __restrict__ bk2,  const float* __restrict__ bm2,
    const float* __restrict__ bc,
    const float* __restrict__ g_att, const float* __restrict__ b_att,
    const float* __restrict__ g_bn,  const float* __restrict__ b_bn,
    const short* __restrict__ wsm,  const float* __restrict__ wsb,
    float* __restrict__ out)
{
  __shared__ short smem[2*16384];    // 64 KB, two 32KB matrix buffers
  const int lane = threadIdx.x & 63;
  const int wid  = threadIdx.x >> 6;
  int tile = blockIdx.x*4 + wid;
  if (tile >= NTILES) tile = NTILES - 1;   // tail waves redo last tile (keeps barriers uniform)
  const int g  = lane >> 4;
  const size_t e = (size_t)tile*16 + (lane & 15);
  const float* erow = edge + e*128;

  // prologue: stage Wq into buf0 while loading edge fragments
  stage_mat(wsm + 0*16384, smem, wid, lane);

  s8v BE[4];
  #pragma unroll
  for (int kk = 0; kk < 4; ++kk) BE[kk] = load_bfrag(erow + kk*32 + g*8);

  f4 acc[8], gm[8];
  s4v qb[8], ekb[8], emb[8], gateb[8];
  s8v S[4], BL[4], BA[4];
  #pragma unroll
  for (int mb = 0; mb < 8; ++mb){ f4 z = {0.f,0.f,0.f,0.f}; gm[mb] = z; }

  __syncthreads();   // drains vmcnt: Wq staged

  // p0: Wq -> qb ; stage GK(1) -> buf1
  stage_mat(wsm + 1*16384, smem + 16384, wid, lane);
  #pragma unroll
  for (int mb = 0; mb < 8; ++mb) acc[mb] = *(const f4*)(bq + mb*16 + g*4);
  mm8l(acc, BE, (const s8v*)smem, lane);
  #pragma unroll
  for (int mb = 0; mb < 8; ++mb){
    s4v t4; t4[0]=f2bf(acc[mb][0]); t4[1]=f2bf(acc[mb][1]); t4[2]=f2bf(acc[mb][2]); t4[3]=f2bf(acc[mb][3]);
    qb[mb] = t4;
  }
  __syncthreads();

  // p1: GK -> ekb ; stage GM(2) -> buf0
  stage_mat(wsm + 2*16384, smem, wid, lane);
  #pragma unroll
  for (int mb = 0; mb < 8; ++mb){ f4 z = {0.f,0.f,0.f,0.f}; acc[mb] = z; }
  mm8l(acc, BE, (const s8v*)(smem + 16384), lane);
  #pragma unroll
  for (int mb = 0; mb < 8; ++mb){
    s4v t4; t4[0]=f2bf(acc[mb][0]); t4[1]=f2bf(acc[mb][1]); t4[2]=f2bf(acc[mb][2]); t4[3]=f2bf(acc[mb][3]);
    ekb[mb] = t4;
  }
  __syncthreads();

  // p2: GM -> emb ; stage GKe0(8) -> buf1 ; prefetch BL/BA for t=0
  stage_mat(wsm + 8*16384, smem + 16384, wid, lane);
  #pragma unroll
  for (int mb = 0; mb < 8; ++mb){ f4 z = {0.f,0.f,0.f,0.f}; acc[mb] = z; }
  mm8l(acc, BE, (const s8v*)smem, lane);
  #pragma unroll
  for (int mb = 0; mb < 8; ++mb){
    s4v t4; t4[0]=f2bf(acc[mb][0]); t4[1]=f2bf(acc[mb][1]); t4[2]=f2bf(acc[mb][2]); t4[3]=f2bf(acc[mb][3]);
    emb[mb] = t4;
  }
  {
    const float* lrow = nlen + e*3*128;
    const float* arow = nang + e*3*128;
    #pragma unroll
    for (int kk = 0; kk < 4; ++kk){
      BL[kk] = load_bfrag(lrow + kk*32 + g*8);
      BA[kk] = load_bfrag(arow + kk*32 + g*8);
    }
  }
  __syncthreads();

  int cur = 1;   // GKe[t] always lands in buf1 at t-loop top (6 flips per t)
  #pragma unroll 1
  for (int t = 0; t < 3; ++t){
    // pA: GKe[t] (B=BL) ; stage GKa(3)
    stage_mat(wsm + 3*16384, smem + (cur^1)*16384, wid, lane);
    #pragma unroll
    for (int mb = 0; mb < 8; ++mb){
      f4 b = *(const f4*)(wsb + t*128 + mb*16 + g*4);
      #pragma unroll
      for (int r = 0; r < 4; ++r) b[r] += bf2f(ekb[mb][r]);
      acc[mb] = b;
    }
    mm8l(acc, BL, (const s8v*)(smem + cur*16384), lane);
    __syncthreads(); cur ^= 1;

    // pB: GKa (B=BA) ; stage Wk2(5) ; silu -> S
    stage_mat(wsm + 5*16384, smem + (cur^1)*16384, wid, lane);
    mm8l(acc, BA, (const s8v*)(smem + cur*16384), lane);
    #pragma unroll
    for (int kk = 0; kk < 4; ++kk){
      #pragma unroll
      for (int p = 0; p < 4; ++p){
        float x0 = acc[2*kk][p];   S[kk][p]   = f2bf(x0 * sigm(x0));
        float x1 = acc[2*kk+1][p]; S[kk][4+p] = f2bf(x1 * sigm(x1));
      }
    }
    __syncthreads(); cur ^= 1;

    // pC: Wk2 (B=S) -> alpha ; LN ; gate ; stage GMe[t](11+t)
    stage_mat(wsm + (size_t)(11+t)*16384, smem + (cur^1)*16384, wid, lane);
    #pragma unroll
    for (int mb = 0; mb < 8; ++mb) acc[mb] = *(const f4*)(bk2 + mb*16 + g*4);
    mm8l(acc, S, (const s8v*)(smem + cur*16384), lane);
    {
      float sm = 0.f, ssq = 0.f;
      #pragma unroll
      for (int mb = 0; mb < 8; ++mb){
        #pragma unroll
        for (int r = 0; r < 4; ++r){
          float a = bf2f(qb[mb][r]) * acc[mb][r] * 0.08838834764831845f;
          acc[mb][r] = a; sm += a; ssq += a*a;
        }
      }
      sm  += __shfl_xor(sm, 16);  sm  += __shfl_xor(sm, 32);
      ssq += __shfl_xor(ssq, 16); ssq += __shfl_xor(ssq, 32);
      float mean = sm * (1.f/128.f);
      float rstd = rsqrtf(ssq * (1.f/128.f) - mean*mean + 1e-5f);
      #pragma unroll
      for (int mb = 0; mb < 8; ++mb){
        f4 ga = *(const f4*)(g_att + mb*16 + g*4);
        f4 bb = *(const f4*)(b_att + mb*16 + g*4);
        s4v t4;
        #pragma unroll
        for (int r = 0; r < 4; ++r)
          t4[r] = f2bf(sigm((acc[mb][r] - mean)*rstd*ga[r] + bb[r]));
        gateb[mb] = t4;
      }
    }
    __syncthreads(); cur ^= 1;

    // pD: GMe[t] (B=BL) ; stage GMa(4)
    stage_mat(wsm + 4*16384, smem + (cur^1)*16384, wid, lane);
    #pragma unroll
    for (int mb = 0; mb < 8; ++mb){
      f4 b = *(const f4*)(wsb + 384 + t*128 + mb*16 + g*4);
      #pragma unroll
      for (int r = 0; r < 4; ++r) b[r] += bf2f(emb[mb][r]);
      acc[mb] = b;
    }
    mm8l(acc, BL, (const s8v*)(smem + cur*16384), lane);
    __syncthreads(); cur ^= 1;

    // pE: GMa (B=BA) ; stage Wm2(6) ; silu -> S
    stage_mat(wsm + 6*16384, smem + (cur^1)*16384, wid, lane);
    mm8l(acc, BA, (const s8v*)(smem + cur*16384), lane);
    #pragma unroll
    for (int kk = 0; kk < 4; ++kk){
      #pragma unroll
      for (int p = 0; p < 4; ++p){
        float x0 = acc[2*kk][p];   S[kk][p]   = f2bf(x0 * sigm(x0));
        float x1 = acc[2*kk+1][p]; S[kk][4+p] = f2bf(x1 * sigm(x1));
      }
    }
    __syncthreads(); cur ^= 1;

    // pF: Wm2 (B=S) -> ma ; gm += ma*gate ; stage next (GKe[t+1] or Wc) ; prefetch BL/BA
    stage_mat(wsm + (size_t)(t < 2 ? 9 + t : 7)*16384, smem + (cur^1)*16384, wid, lane);
    #pragma unroll
    for (int mb = 0; mb < 8; ++mb) acc[mb] = *(const f4*)(bm2 + mb*16 + g*4);
    mm8l(acc, S, (const s8v*)(smem + cur*16384), lane);
    if (t < 2){
      const float* lrow = nlen + (e*3 + t + 1)*128;
      const float* arow = nang + (e*3 + t + 1)*128;
      #pragma unroll
      for (int kk = 0; kk < 4; ++kk){
        BL[kk] = load_bfrag(lrow + kk*32 + g*8);
        BA[kk] = load_bfrag(arow + kk*32 + g*8);
      }
    }
    #pragma unroll
    for (int mb = 0; mb < 8; ++mb){
      #pragma unroll
      for (int r = 0; r < 4; ++r) gm[mb][r] += acc[mb][r] * bf2f(gateb[mb][r]);
    }
    __syncthreads(); cur ^= 1;
  }

  // p21: Wc (B=gm as dlay fragments) ; LN ; softplus(edge + .) ; store
  s8v GF[4];
  #pragma unroll
  for (int kk = 0; kk < 4; ++kk){
    #pragma unroll
    for (int p = 0; p < 4; ++p){
      GF[kk][p]   = f2bf(gm[2*kk][p]);
      GF[kk][4+p] = f2bf(gm[2*kk+1][p]);
    }
  }
  #pragma unroll
  for (int mb = 0; mb < 8; ++mb){
    f4 b = *(const f4*)(bc + mb*16 + g*4);
    #pragma unroll
    for (int r = 0; r < 4; ++r) b[r] *= 3.f;
    acc[mb] = b;
  }
  mm8l(acc, GF, (const s8v*)(smem + cur*16384), lane);

  float sm = 0.f, ssq = 0.f;
  #pragma unroll
  for (int mb = 0; mb < 8; ++mb){
    #pragma unroll
    for (int r = 0; r < 4; ++r){ sm += acc[mb][r]; ssq += acc[mb][r]*acc[mb][r]; }
  }
  sm  += __shfl_xor(sm, 16);  sm  += __shfl_xor(sm, 32);
  ssq += __shfl_xor(ssq, 16); ssq += __shfl_xor(ssq, 32);
  float mean = sm * (1.f/128.f);
  float rstd = rsqrtf(ssq * (1.f/128.f) - mean*mean + 1e-5f);

  #pragma unroll
  for (int mb = 0; mb < 8; ++mb){
    f4 ev  = *(const f4*)(erow + mb*16 + g*4);
    f4 gv  = *(const f4*)(g_bn + mb*16 + g*4);
    f4 bv2 = *(const f4*)(b_bn + mb*16 + g*4);
    f4 o;
    #pragma unroll
    for (int r = 0; r < 4; ++r){
      float x = ev[r] + (acc[mb][r] - mean)*rstd*gv[r] + bv2[r];
      o[r] = (x > 20.f) ? x : log1pf(__expf(x));
    }
    *(f4*)(out + e*128 + mb*16 + g*4) = o;
  }
}

extern "C" void kernel_launch(void* const* d_in, const int* in_sizes, int n_in,
                              void* d_out, int out_size, void* d_ws, size_t ws_size,
                              hipStream_t stream)
{
  const float* edge = (const float*)d_in[0];
  const float* nlen = (const float*)d_in[1];
  const float* nang = (const float*)d_in[2];
  const float* Wq  = (const float*)d_in[3];
  const float* bq  = (const float*)d_in[4];
  const float* Wk  = (const float*)d_in[5];
  const float* bk  = (const float*)d_in[6];
  const float* Wv  = (const float*)d_in[7];
  const float* bv  = (const float*)d_in[8];
  const float* Wke = (const float*)d_in[9];
  const float* bke = (const float*)d_in[10];
  const float* Wve = (const float*)d_in[11];
  const float* bve = (const float*)d_in[12];
  const float* We  = (const float*)d_in[13];
  const float* Wc  = (const float*)d_in[14];
  const float* bc  = (const float*)d_in[15];
  const float* Wk1 = (const float*)d_in[16];
  const float* bk1 = (const float*)d_in[17];
  const float* Wk2 = (const float*)d_in[18];
  const float* bk2 = (const float*)d_in[19];
  const float* Wm1 = (const float*)d_in[20];
  const float* bm1 = (const float*)d_in[21];
  const float* Wm2 = (const float*)d_in[22];
  const float* bm2 = (const float*)d_in[23];
  const float* g_att = (const float*)d_in[24];
  const float* b_att = (const float*)d_in[25];
  const float* g_bn  = (const float*)d_in[26];
  const float* b_bn  = (const float*)d_in[27];

  // ws layout: 14 packed bf16 matrices (16384 shorts each) + 6*128 f32 biases
  short* wsm = (short*)d_ws;
  float* wsb = (float*)((char*)d_ws + (size_t)14*16384*2);

  pack_weights<<<dim3(14*64), dim3(256), 0, stream>>>(
      Wq, Wk, Wv, Wke, Wve, We, Wc, Wk1, Wk2, Wm1, Wm2, wsm);
  make_biases<<<dim3(6), dim3(128), 0, stream>>>(
      bk, bke, bk1, bv, bve, bm1, Wk1, Wm1, wsb);
  edge_main<<<dim3((NTILES + 3)/4), dim3(256), 0, stream>>>(
      edge, nlen, nang, bq, bk2, bm2, bc, g_att, b_att, g_bn, b_bn,
      wsm, wsb, (float*)d_out);
}